// Round 2
// baseline (1475.245 us; speedup 1.0000x reference)
//
#include <hip/hip_runtime.h>

#define N_NODES 100000
#define N_EDGES 1600000
#define D 64

// ---------------------------------------------------------------------------
// Kernel 1: out = x   (self term: h = (1+eps)*x + sum_neighbors, eps = 0)
// ---------------------------------------------------------------------------
__global__ void init_h(const float4* __restrict__ x, float4* __restrict__ h,
                       int n4) {
    int i = blockIdx.x * blockDim.x + threadIdx.x;
    if (i < n4) h[i] = x[i];
}

// ---------------------------------------------------------------------------
// Kernel 2: scatter-add x[src] into h[dst] over all edges.
// One thread per (edge, 16-byte chunk): 16 threads cover one 64-float row.
// NOTE: harness stores integer inputs as int32 (even though reference is
// int64) — read edge_index as const int*.
// ---------------------------------------------------------------------------
__global__ void scatter_add(const float4* __restrict__ x4,
                            const int* __restrict__ ei,
                            float* __restrict__ h) {
    long long i = (long long)blockIdx.x * blockDim.x + threadIdx.x;
    const long long nwork = (long long)N_EDGES * 16;
    if (i >= nwork) return;
    int e = (int)(i >> 4);
    int lane = (int)(i & 15);
    int src = ei[e];
    int dst = ei[N_EDGES + e];
    float4 v = x4[(long long)src * 16 + lane];
    float* p = h + (long long)dst * 64 + lane * 4;
    unsafeAtomicAdd(p + 0, v.x);
    unsafeAtomicAdd(p + 1, v.y);
    unsafeAtomicAdd(p + 2, v.z);
    unsafeAtomicAdd(p + 3, v.w);
}

// ---------------------------------------------------------------------------
// Kernel 3: two-layer MLP, in place on h (= d_out).
// 256 threads/block = 4 nodes/block, one 64-lane wave per node.
// ---------------------------------------------------------------------------
__global__ __launch_bounds__(256) void mlp(float* __restrict__ h,
                                           const float* __restrict__ W1,
                                           const float* __restrict__ b1,
                                           const float* __restrict__ W2,
                                           const float* __restrict__ b2) {
    __shared__ float sW1[64][64];
    __shared__ float sW2[64][64];
    __shared__ float sb1[64];
    __shared__ float sb2[64];
    __shared__ float sh[4][64];
    __shared__ float sh1[4][64];

    int tid = threadIdx.x;
    for (int i = tid; i < 4096; i += 256) {
        sW1[i >> 6][i & 63] = W1[i];
        sW2[i >> 6][i & 63] = W2[i];
    }
    if (tid < 64) {
        sb1[tid] = b1[tid];
        sb2[tid] = b2[tid];
    }
    __syncthreads();

    int local = tid >> 6;   // which of the 4 nodes in this block
    int j = tid & 63;       // output feature index
    int node = blockIdx.x * 4 + local;   // grid sized so node < N_NODES always

    sh[local][j] = h[(long long)node * 64 + j];
    __syncthreads();

    float acc = sb1[j];
#pragma unroll
    for (int k = 0; k < 64; ++k) acc = fmaf(sh[local][k], sW1[k][j], acc);
    acc = fmaxf(acc, 0.0f);
    sh1[local][j] = acc;
    __syncthreads();

    float acc2 = sb2[j];
#pragma unroll
    for (int k = 0; k < 64; ++k) acc2 = fmaf(sh1[local][k], sW2[k][j], acc2);
    h[(long long)node * 64 + j] = acc2;
}

extern "C" void kernel_launch(void* const* d_in, const int* in_sizes, int n_in,
                              void* d_out, int out_size, void* d_ws, size_t ws_size,
                              hipStream_t stream) {
    const float* x = (const float*)d_in[0];
    const int* ei = (const int*)d_in[1];   // harness stores ints as int32
    const float* W1 = (const float*)d_in[2];
    const float* b1 = (const float*)d_in[3];
    const float* W2 = (const float*)d_in[4];
    const float* b2 = (const float*)d_in[5];
    float* out = (float*)d_out;

    // 1) out = x
    int n4 = N_NODES * D / 4;                 // 1.6M float4
    init_h<<<(n4 + 255) / 256, 256, 0, stream>>>((const float4*)x, (float4*)out, n4);

    // 2) out += scatter(x[src] -> dst)
    long long nwork = (long long)N_EDGES * 16;
    int scatBlocks = (int)((nwork + 255) / 256);   // 100000 blocks
    scatter_add<<<scatBlocks, 256, 0, stream>>>((const float4*)x, ei, out);

    // 3) MLP in place. 100000 / 4 = 25000 blocks exactly.
    mlp<<<N_NODES / 4, 256, 0, stream>>>(out, W1, b1, W2, b2);
}

// Round 3
// 456.535 us; speedup vs baseline: 3.2314x; 3.2314x over previous
//
#include <hip/hip_runtime.h>

#define N_NODES 100000
#define N_EDGES 1600000
#define D 64

#define SCAN_CHUNK 2048
#define SCAN_BLOCKS ((N_NODES + SCAN_CHUNK - 1) / SCAN_CHUNK)   // 49

// ---------------------------------------------------------------------------
// CSR-build path: count -> scan -> fill -> gather+MLP (no float atomics).
// ws layout (ints): deg[N] | offs[N] | bsum[SCAN_BLOCKS] | csr[E]
// ---------------------------------------------------------------------------

__global__ void zero_ints(int* __restrict__ p, int n) {
    int i = blockIdx.x * blockDim.x + threadIdx.x;
    if (i < n) p[i] = 0;
}

__global__ void count_deg(const int* __restrict__ ei, int* __restrict__ deg) {
    int e = blockIdx.x * blockDim.x + threadIdx.x;
    if (e < N_EDGES) atomicAdd(&deg[ei[N_EDGES + e]], 1);
}

// Exclusive scan, 3 phases. Phase A: per-block scan of 2048-chunks.
__global__ __launch_bounds__(256) void scan_a(const int* __restrict__ deg,
                                              int* __restrict__ offs,
                                              int* __restrict__ bsum) {
    __shared__ int lds[256];
    int tid = threadIdx.x;
    int base = blockIdx.x * SCAN_CHUNK + tid * 8;
    int v[8], ex[8];
    int run = 0;
#pragma unroll
    for (int k = 0; k < 8; ++k) {
        v[k] = (base + k < N_NODES) ? deg[base + k] : 0;
        ex[k] = run;
        run += v[k];
    }
    lds[tid] = run;
    __syncthreads();
    for (int off = 1; off < 256; off <<= 1) {
        int t = (tid >= off) ? lds[tid - off] : 0;
        __syncthreads();
        lds[tid] += t;
        __syncthreads();
    }
    int prefix = lds[tid] - run;   // exclusive prefix of this thread's chunk
#pragma unroll
    for (int k = 0; k < 8; ++k)
        if (base + k < N_NODES) offs[base + k] = prefix + ex[k];
    if (tid == 0) bsum[blockIdx.x] = lds[255];
}

// Phase B: serial exclusive scan of the 49 block totals (trivial).
__global__ void scan_b(int* __restrict__ bsum) {
    if (threadIdx.x == 0 && blockIdx.x == 0) {
        int run = 0;
        for (int b = 0; b < SCAN_BLOCKS; ++b) {
            int t = bsum[b];
            bsum[b] = run;
            run += t;
        }
    }
}

// Phase C: add block offsets.
__global__ void scan_c(int* __restrict__ offs, const int* __restrict__ bsum) {
    int i = blockIdx.x * blockDim.x + threadIdx.x;
    if (i < N_NODES) offs[i] += bsum[i / SCAN_CHUNK];
}

// Fill CSR. After this kernel, offs[d] = END index of node d's list
// (original exclusive start + degree). Start of node d = offs[d-1] (0 for d=0).
__global__ void fill_csr(const int* __restrict__ ei, int* __restrict__ offs,
                         int* __restrict__ csr) {
    int e = blockIdx.x * blockDim.x + threadIdx.x;
    if (e >= N_EDGES) return;
    int src = ei[e];
    int dst = ei[N_EDGES + e];
    int pos = atomicAdd(&offs[dst], 1);
    csr[pos] = src;
}

// Fused gather-sum + 2-layer MLP. One 64-lane wave per node, 4 nodes/block.
// Lane j owns feature j. Neighbor rows: coalesced 256B loads from cache-
// resident x. Neighbor indices: one coalesced 64-wide load per chunk, then
// broadcast via __shfl.
__global__ __launch_bounds__(256) void gather_mlp(
    const float* __restrict__ x, const int* __restrict__ offs,
    const int* __restrict__ csr, float* __restrict__ out,
    const float* __restrict__ W1, const float* __restrict__ b1,
    const float* __restrict__ W2, const float* __restrict__ b2) {
    __shared__ float sW1[64][64];
    __shared__ float sW2[64][64];
    __shared__ float sb1[64];
    __shared__ float sb2[64];
    __shared__ float sh[4][64];
    __shared__ float sh1[4][64];

    int tid = threadIdx.x;
    for (int i = tid; i < 4096; i += 256) {
        sW1[i >> 6][i & 63] = W1[i];
        sW2[i >> 6][i & 63] = W2[i];
    }
    if (tid < 64) {
        sb1[tid] = b1[tid];
        sb2[tid] = b2[tid];
    }

    int local = tid >> 6;
    int j = tid & 63;                    // lane == feature index
    int node = blockIdx.x * 4 + local;   // grid exact: node < N_NODES

    int start = (node == 0) ? 0 : offs[node - 1];
    int end = offs[node];

    float acc = x[(long long)node * 64 + j];   // self term (eps = 0)
    for (int b = start; b < end; b += 64) {
        int n = min(64, end - b);
        int myv = (b + j < end) ? csr[b + j] : 0;
#pragma unroll 4
        for (int t = 0; t < n; ++t) {
            int src = __shfl(myv, t);
            acc += x[(long long)src * 64 + j];
        }
    }

    __syncthreads();   // weights staged + all waves ready
    sh[local][j] = acc;
    __syncthreads();

    float a1 = sb1[j];
#pragma unroll
    for (int k = 0; k < 64; ++k) a1 = fmaf(sh[local][k], sW1[k][j], a1);
    a1 = fmaxf(a1, 0.0f);
    sh1[local][j] = a1;
    __syncthreads();

    float a2 = sb2[j];
#pragma unroll
    for (int k = 0; k < 64; ++k) a2 = fmaf(sh1[local][k], sW2[k][j], a2);
    out[(long long)node * 64 + j] = a2;
}

// ---------------------------------------------------------------------------
// Fallback path (proven in round 2): fp32-atomic scatter. Used only if the
// workspace is too small for CSR.
// ---------------------------------------------------------------------------
__global__ void init_h(const float4* __restrict__ x, float4* __restrict__ h,
                       int n4) {
    int i = blockIdx.x * blockDim.x + threadIdx.x;
    if (i < n4) h[i] = x[i];
}

__global__ void scatter_add(const float4* __restrict__ x4,
                            const int* __restrict__ ei,
                            float* __restrict__ h) {
    long long i = (long long)blockIdx.x * blockDim.x + threadIdx.x;
    if (i >= (long long)N_EDGES * 16) return;
    int e = (int)(i >> 4);
    int lane = (int)(i & 15);
    int src = ei[e];
    int dst = ei[N_EDGES + e];
    float4 v = x4[(long long)src * 16 + lane];
    float* p = h + (long long)dst * 64 + lane * 4;
    unsafeAtomicAdd(p + 0, v.x);
    unsafeAtomicAdd(p + 1, v.y);
    unsafeAtomicAdd(p + 2, v.z);
    unsafeAtomicAdd(p + 3, v.w);
}

__global__ __launch_bounds__(256) void mlp(float* __restrict__ h,
                                           const float* __restrict__ W1,
                                           const float* __restrict__ b1,
                                           const float* __restrict__ W2,
                                           const float* __restrict__ b2) {
    __shared__ float sW1[64][64];
    __shared__ float sW2[64][64];
    __shared__ float sb1[64];
    __shared__ float sb2[64];
    __shared__ float sh[4][64];
    __shared__ float sh1[4][64];
    int tid = threadIdx.x;
    for (int i = tid; i < 4096; i += 256) {
        sW1[i >> 6][i & 63] = W1[i];
        sW2[i >> 6][i & 63] = W2[i];
    }
    if (tid < 64) { sb1[tid] = b1[tid]; sb2[tid] = b2[tid]; }
    __syncthreads();
    int local = tid >> 6, j = tid & 63;
    int node = blockIdx.x * 4 + local;
    sh[local][j] = h[(long long)node * 64 + j];
    __syncthreads();
    float acc = sb1[j];
#pragma unroll
    for (int k = 0; k < 64; ++k) acc = fmaf(sh[local][k], sW1[k][j], acc);
    acc = fmaxf(acc, 0.0f);
    sh1[local][j] = acc;
    __syncthreads();
    float acc2 = sb2[j];
#pragma unroll
    for (int k = 0; k < 64; ++k) acc2 = fmaf(sh1[local][k], sW2[k][j], acc2);
    h[(long long)node * 64 + j] = acc2;
}

extern "C" void kernel_launch(void* const* d_in, const int* in_sizes, int n_in,
                              void* d_out, int out_size, void* d_ws, size_t ws_size,
                              hipStream_t stream) {
    const float* x = (const float*)d_in[0];
    const int* ei = (const int*)d_in[1];   // harness stores ints as int32
    const float* W1 = (const float*)d_in[2];
    const float* b1 = (const float*)d_in[3];
    const float* W2 = (const float*)d_in[4];
    const float* b2 = (const float*)d_in[5];
    float* out = (float*)d_out;

    size_t need = (size_t)(2 * N_NODES + SCAN_BLOCKS + N_EDGES) * sizeof(int);
    if (ws_size >= need) {
        int* deg = (int*)d_ws;
        int* offs = deg + N_NODES;
        int* bsum = offs + N_NODES;
        int* csr = bsum + SCAN_BLOCKS;

        zero_ints<<<(N_NODES + 255) / 256, 256, 0, stream>>>(deg, N_NODES);
        count_deg<<<(N_EDGES + 255) / 256, 256, 0, stream>>>(ei, deg);
        scan_a<<<SCAN_BLOCKS, 256, 0, stream>>>(deg, offs, bsum);
        scan_b<<<1, 64, 0, stream>>>(bsum);
        scan_c<<<(N_NODES + 255) / 256, 256, 0, stream>>>(offs, bsum);
        fill_csr<<<(N_EDGES + 255) / 256, 256, 0, stream>>>(ei, offs, csr);
        gather_mlp<<<N_NODES / 4, 256, 0, stream>>>(x, offs, csr, out,
                                                    W1, b1, W2, b2);
    } else {
        int n4 = N_NODES * D / 4;
        init_h<<<(n4 + 255) / 256, 256, 0, stream>>>((const float4*)x,
                                                     (float4*)out, n4);
        long long nwork = (long long)N_EDGES * 16;
        scatter_add<<<(int)((nwork + 255) / 256), 256, 0, stream>>>(
            (const float4*)x, ei, out);
        mlp<<<N_NODES / 4, 256, 0, stream>>>(out, W1, b1, W2, b2);
    }
}

// Round 4
// 316.866 us; speedup vs baseline: 4.6557x; 1.4408x over previous
//
#include <hip/hip_runtime.h>

#define N_NODES 100000
#define N_EDGES 1600000

#define SCAN_CHUNK 2048
#define SCAN_BLOCKS ((N_NODES + SCAN_CHUNK - 1) / SCAN_CHUNK)   // 49

// ---------------------------------------------------------------------------
// CSR-build path: count -> scan_a -> scan_c(+fused block prefix) -> fill ->
// fused gather+MLP. ws layout (ints): deg[N] | offs[N] | bsum[49] | csr[E]
// ---------------------------------------------------------------------------

__global__ void zero_ints(int* __restrict__ p, int n) {
    int i = blockIdx.x * blockDim.x + threadIdx.x;
    if (i < n) p[i] = 0;
}

__global__ void count_deg(const int* __restrict__ ei, int* __restrict__ deg) {
    int e = blockIdx.x * blockDim.x + threadIdx.x;
    if (e < N_EDGES) atomicAdd(&deg[ei[N_EDGES + e]], 1);
}

// Per-2048-chunk exclusive scan; bsum[b] = chunk total (raw, not scanned).
__global__ __launch_bounds__(256) void scan_a(const int* __restrict__ deg,
                                              int* __restrict__ offs,
                                              int* __restrict__ bsum) {
    __shared__ int lds[256];
    int tid = threadIdx.x;
    int base = blockIdx.x * SCAN_CHUNK + tid * 8;
    int v[8], ex[8];
    int run = 0;
#pragma unroll
    for (int k = 0; k < 8; ++k) {
        v[k] = (base + k < N_NODES) ? deg[base + k] : 0;
        ex[k] = run;
        run += v[k];
    }
    lds[tid] = run;
    __syncthreads();
    for (int off = 1; off < 256; off <<= 1) {
        int t = (tid >= off) ? lds[tid - off] : 0;
        __syncthreads();
        lds[tid] += t;
        __syncthreads();
    }
    int prefix = lds[tid] - run;
#pragma unroll
    for (int k = 0; k < 8; ++k)
        if (base + k < N_NODES) offs[base + k] = prefix + ex[k];
    if (tid == 0) bsum[blockIdx.x] = lds[255];
}

// Add cross-chunk prefix (computed inline: <=48 adds over cached bsum).
__global__ void scan_c(int* __restrict__ offs, const int* __restrict__ bsum) {
    int i = blockIdx.x * blockDim.x + threadIdx.x;
    if (i >= N_NODES) return;
    int chunk = i / SCAN_CHUNK;
    int add = 0;
    for (int t = 0; t < chunk; ++t) add += bsum[t];
    offs[i] += add;
}

// After fill: offs[d] = end of node d's list; start = offs[d-1] (0 for d=0).
__global__ void fill_csr(const int* __restrict__ ei, int* __restrict__ offs,
                         int* __restrict__ csr) {
    int e = blockIdx.x * blockDim.x + threadIdx.x;
    if (e >= N_EDGES) return;
    int src = ei[e];
    int dst = ei[N_EDGES + e];
    int pos = atomicAdd(&offs[dst], 1);
    csr[pos] = src;
}

// ---------------------------------------------------------------------------
// Fused gather-sum + 2-layer MLP.
// 512 threads = 8 waves = 8 nodes/block. Gather wave layout: lane = (s,c),
// s = lane>>4 in [0,4) neighbor slot, c = lane&15 float4 chunk. Each batch
// of 16 neighbors issues 4 independent index loads + 4 independent float4
// row gathers per lane -> high memory-level parallelism, no shfl in loop.
// LDS ~36.5 KB -> 4 blocks/CU -> 32 waves/CU (full occupancy).
// ---------------------------------------------------------------------------
__global__ __launch_bounds__(512) void gather_mlp(
    const float4* __restrict__ x4, const int* __restrict__ offs,
    const int* __restrict__ csr, float* __restrict__ out,
    const float* __restrict__ W1, const float* __restrict__ b1,
    const float* __restrict__ W2, const float* __restrict__ b2) {
    __shared__ float sW1[64][64];
    __shared__ float sW2[64][64];
    __shared__ float sb1[64];
    __shared__ float sb2[64];
    __shared__ float sh[8][64];
    __shared__ float sh1[8][64];

    int tid = threadIdx.x;
    // Stage weights; overlaps with the gather loop (no sync until after it).
    for (int i = tid; i < 4096; i += 512) {
        sW1[i >> 6][i & 63] = W1[i];
        sW2[i >> 6][i & 63] = W2[i];
    }
    if (tid < 64) {
        sb1[tid] = b1[tid];
        sb2[tid] = b2[tid];
    }

    int local = tid >> 6;          // wave id == node slot in block
    int lane = tid & 63;
    int s = lane >> 4;             // neighbor slot
    int c = lane & 15;             // float4 chunk of the 64-float row
    int node = blockIdx.x * 8 + local;   // grid exact: node < N_NODES

    int start = (node == 0) ? 0 : offs[node - 1];
    int end = offs[node];

    float4 acc = make_float4(0.f, 0.f, 0.f, 0.f);
    float4 self = x4[(size_t)node * 16 + c];
    if (s == 0) acc = self;        // self term (eps = 0)

    for (int b = start; b < end; b += 16) {
        int p = b + s;
        int i0 = (p < end) ? csr[p] : -1;
        int i1 = (p + 4 < end) ? csr[p + 4] : -1;
        int i2 = (p + 8 < end) ? csr[p + 8] : -1;
        int i3 = (p + 12 < end) ? csr[p + 12] : -1;
        float4 v0 = x4[(size_t)max(i0, 0) * 16 + c];
        float4 v1 = x4[(size_t)max(i1, 0) * 16 + c];
        float4 v2 = x4[(size_t)max(i2, 0) * 16 + c];
        float4 v3 = x4[(size_t)max(i3, 0) * 16 + c];
        if (i0 >= 0) { acc.x += v0.x; acc.y += v0.y; acc.z += v0.z; acc.w += v0.w; }
        if (i1 >= 0) { acc.x += v1.x; acc.y += v1.y; acc.z += v1.z; acc.w += v1.w; }
        if (i2 >= 0) { acc.x += v2.x; acc.y += v2.y; acc.z += v2.z; acc.w += v2.w; }
        if (i3 >= 0) { acc.x += v3.x; acc.y += v3.y; acc.z += v3.z; acc.w += v3.w; }
    }

    // Reduce the 4 neighbor slots.
    acc.x += __shfl_xor(acc.x, 16); acc.y += __shfl_xor(acc.y, 16);
    acc.z += __shfl_xor(acc.z, 16); acc.w += __shfl_xor(acc.w, 16);
    acc.x += __shfl_xor(acc.x, 32); acc.y += __shfl_xor(acc.y, 32);
    acc.z += __shfl_xor(acc.z, 32); acc.w += __shfl_xor(acc.w, 32);

    __syncthreads();   // weights staged; sh first touched below
    if (s == 0) *(float4*)&sh[local][c * 4] = acc;
    __syncthreads();

    int j = lane;      // output feature index
    float a1 = sb1[j];
#pragma unroll
    for (int k = 0; k < 64; ++k) a1 = fmaf(sh[local][k], sW1[k][j], a1);
    a1 = fmaxf(a1, 0.0f);
    sh1[local][j] = a1;
    __syncthreads();

    float a2 = sb2[j];
#pragma unroll
    for (int k = 0; k < 64; ++k) a2 = fmaf(sh1[local][k], sW2[k][j], a2);
    out[(size_t)node * 64 + j] = a2;
}

// ---------------------------------------------------------------------------
// Fallback (round-2-proven) fp32-atomic path, used only if ws is too small.
// ---------------------------------------------------------------------------
__global__ void init_h(const float4* __restrict__ x, float4* __restrict__ h,
                       int n4) {
    int i = blockIdx.x * blockDim.x + threadIdx.x;
    if (i < n4) h[i] = x[i];
}

__global__ void scatter_add(const float4* __restrict__ x4,
                            const int* __restrict__ ei,
                            float* __restrict__ h) {
    long long i = (long long)blockIdx.x * blockDim.x + threadIdx.x;
    if (i >= (long long)N_EDGES * 16) return;
    int e = (int)(i >> 4);
    int lane = (int)(i & 15);
    int src = ei[e];
    int dst = ei[N_EDGES + e];
    float4 v = x4[(long long)src * 16 + lane];
    float* p = h + (long long)dst * 64 + lane * 4;
    unsafeAtomicAdd(p + 0, v.x);
    unsafeAtomicAdd(p + 1, v.y);
    unsafeAtomicAdd(p + 2, v.z);
    unsafeAtomicAdd(p + 3, v.w);
}

__global__ __launch_bounds__(256) void mlp(float* __restrict__ h,
                                           const float* __restrict__ W1,
                                           const float* __restrict__ b1,
                                           const float* __restrict__ W2,
                                           const float* __restrict__ b2) {
    __shared__ float sW1[64][64];
    __shared__ float sW2[64][64];
    __shared__ float sb1[64];
    __shared__ float sb2[64];
    __shared__ float sh[4][64];
    __shared__ float sh1[4][64];
    int tid = threadIdx.x;
    for (int i = tid; i < 4096; i += 256) {
        sW1[i >> 6][i & 63] = W1[i];
        sW2[i >> 6][i & 63] = W2[i];
    }
    if (tid < 64) { sb1[tid] = b1[tid]; sb2[tid] = b2[tid]; }
    __syncthreads();
    int local = tid >> 6, j = tid & 63;
    int node = blockIdx.x * 4 + local;
    sh[local][j] = h[(long long)node * 64 + j];
    __syncthreads();
    float acc = sb1[j];
#pragma unroll
    for (int k = 0; k < 64; ++k) acc = fmaf(sh[local][k], sW1[k][j], acc);
    acc = fmaxf(acc, 0.0f);
    sh1[local][j] = acc;
    __syncthreads();
    float acc2 = sb2[j];
#pragma unroll
    for (int k = 0; k < 64; ++k) acc2 = fmaf(sh1[local][k], sW2[k][j], acc2);
    h[(long long)node * 64 + j] = acc2;
}

extern "C" void kernel_launch(void* const* d_in, const int* in_sizes, int n_in,
                              void* d_out, int out_size, void* d_ws, size_t ws_size,
                              hipStream_t stream) {
    const float* x = (const float*)d_in[0];
    const int* ei = (const int*)d_in[1];   // harness stores ints as int32
    const float* W1 = (const float*)d_in[2];
    const float* b1 = (const float*)d_in[3];
    const float* W2 = (const float*)d_in[4];
    const float* b2 = (const float*)d_in[5];
    float* out = (float*)d_out;

    size_t need = (size_t)(2 * N_NODES + SCAN_BLOCKS + N_EDGES) * sizeof(int);
    if (ws_size >= need) {
        int* deg = (int*)d_ws;
        int* offs = deg + N_NODES;
        int* bsum = offs + N_NODES;
        int* csr = bsum + SCAN_BLOCKS;

        zero_ints<<<(N_NODES + 255) / 256, 256, 0, stream>>>(deg, N_NODES);
        count_deg<<<(N_EDGES + 255) / 256, 256, 0, stream>>>(ei, deg);
        scan_a<<<SCAN_BLOCKS, 256, 0, stream>>>(deg, offs, bsum);
        scan_c<<<(N_NODES + 255) / 256, 256, 0, stream>>>(offs, bsum);
        fill_csr<<<(N_EDGES + 255) / 256, 256, 0, stream>>>(ei, offs, csr);
        gather_mlp<<<N_NODES / 8, 512, 0, stream>>>((const float4*)x, offs,
                                                    csr, out, W1, b1, W2, b2);
    } else {
        int n4 = N_NODES * 64 / 4;
        init_h<<<(n4 + 255) / 256, 256, 0, stream>>>((const float4*)x,
                                                     (float4*)out, n4);
        long long nwork = (long long)N_EDGES * 16;
        scatter_add<<<(int)((nwork + 255) / 256), 256, 0, stream>>>(
            (const float4*)x, ei, out);
        mlp<<<N_NODES / 4, 256, 0, stream>>>(out, W1, b1, W2, b2);
    }
}

// Round 5
// 164.216 us; speedup vs baseline: 8.9836x; 1.9296x over previous
//
#include <hip/hip_runtime.h>

#define N_NODES 100000
#define N_EDGES 1600000

// --- bucket-sort build parameters ---
#define SPAN 256                      // nodes per bucket (dst >> 8)
#define NB 391                        // ceil(100000/256)
#define NBLK_A 256                    // blocks in count/bin kernels
#define EPB (N_EDGES / NBLK_A)        // 6250 edges per block (exact)

// --- legacy (round-4) path parameters ---
#define SCAN_CHUNK 2048
#define SCAN_BLOCKS ((N_NODES + SCAN_CHUNK - 1) / SCAN_CHUNK)

// ===========================================================================
// NEW build: deterministic two-level bucket sort, no global atomics.
// ws (ints): offs[N] | M[NBLK_A*NB] | bcount[NB] | bbase[NB+1] | binned[E] | csr[E]
// ===========================================================================

// A1: per-(block,bucket) histogram.
__global__ __launch_bounds__(256) void count_buckets(const int* __restrict__ ei,
                                                     int* __restrict__ M) {
    __shared__ int hist[NB];
    int tid = threadIdx.x;
    for (int i = tid; i < NB; i += 256) hist[i] = 0;
    __syncthreads();
    int e0 = blockIdx.x * EPB;
    for (int e = e0 + tid; e < e0 + EPB; e += 256)
        atomicAdd(&hist[ei[N_EDGES + e] >> 8], 1);
    __syncthreads();
    for (int i = tid; i < NB; i += 256) M[blockIdx.x * NB + i] = hist[i];
}

// A2: column scan — M[k][b] becomes exclusive offset of block k within bucket b.
__global__ void col_scan(int* __restrict__ M, int* __restrict__ bcount) {
    int b = blockIdx.x * blockDim.x + threadIdx.x;
    if (b >= NB) return;
    int s = 0;
    for (int k = 0; k < NBLK_A; ++k) {      // M[k*NB+b]: coalesced across threads
        int idx = k * NB + b;
        int t = M[idx];
        M[idx] = s;
        s += t;
    }
    bcount[b] = s;
}

// A2b: exclusive scan of bucket counts -> global bucket bases. bbase[NB] = E.
__global__ __launch_bounds__(512) void bucket_base(const int* __restrict__ bcount,
                                                   int* __restrict__ bbase) {
    __shared__ int s[512];
    int tid = threadIdx.x;
    int v = (tid < NB) ? bcount[tid] : 0;
    s[tid] = v;
    __syncthreads();
    for (int off = 1; off < 512; off <<= 1) {
        int t = (tid >= off) ? s[tid - off] : 0;
        __syncthreads();
        s[tid] += t;
        __syncthreads();
    }
    if (tid < NB) bbase[tid] = s[tid] - v;
    if (tid == NB - 1) bbase[NB] = s[tid];
}

// A3: bin edges. Each block writes only its own contiguous slice per bucket
// -> csr lines are single-XCD -> full-line write-backs (no 64B-per-4B blowup).
__global__ __launch_bounds__(256) void bin_edges(const int* __restrict__ ei,
                                                 const int* __restrict__ M,
                                                 const int* __restrict__ bbase,
                                                 int* __restrict__ binned) {
    __shared__ int sbase[NB];
    __shared__ int cur[NB];
    int tid = threadIdx.x;
    for (int i = tid; i < NB; i += 256) {
        sbase[i] = bbase[i] + M[blockIdx.x * NB + i];
        cur[i] = 0;
    }
    __syncthreads();
    int e0 = blockIdx.x * EPB;
    for (int e = e0 + tid; e < e0 + EPB; e += 256) {
        int d = ei[N_EDGES + e];
        int s = ei[e];
        int b = d >> 8;
        int r = atomicAdd(&cur[b], 1);                 // LDS cursor
        binned[sbase[b] + r] = (s << 8) | (d & 255);   // src:17b | local_dst:8b
    }
}

// B: per-bucket counting sort by local dst -> csr (sorted by dst) + offs (ends).
__global__ __launch_bounds__(256) void bucket_sort(const int* __restrict__ binned,
                                                   const int* __restrict__ bbase,
                                                   int* __restrict__ csr,
                                                   int* __restrict__ offs) {
    __shared__ int lh[256];
    __shared__ int ls[256];
    __shared__ int lc[256];
    int tid = threadIdx.x;
    int b = blockIdx.x;
    int base = bbase[b];
    int cnt = bbase[b + 1] - base;

    lh[tid] = 0;
    __syncthreads();
    for (int i = tid; i < cnt; i += 256)
        atomicAdd(&lh[binned[base + i] & 255], 1);
    __syncthreads();

    int own = lh[tid];
    ls[tid] = own;
    __syncthreads();
    for (int off = 1; off < 256; off <<= 1) {      // inclusive scan
        int t = (tid >= off) ? ls[tid - off] : 0;
        __syncthreads();
        ls[tid] += t;
        __syncthreads();
    }

    int node = b * SPAN + tid;
    if (node < N_NODES) offs[node] = base + ls[tid];   // end of node's segment

    int ex = ls[tid] - own;
    __syncthreads();
    ls[tid] = ex;                                  // exclusive start
    lc[tid] = 0;
    __syncthreads();
    for (int i = tid; i < cnt; i += 256) {
        int en = binned[base + i];
        int ld = en & 255;
        int r = atomicAdd(&lc[ld], 1);
        csr[base + ls[ld] + r] = en >> 8;          // single-XCD 16KB region
    }
}

// ===========================================================================
// Fused gather-sum + 2-layer MLP (unchanged from round 4).
// 512 threads = 8 waves = 8 nodes/block; lane = (s,c): 4 neighbor slots x 16
// float4 chunks -> 4 independent gathers in flight per lane, no shfl in loop.
// ===========================================================================
__global__ __launch_bounds__(512) void gather_mlp(
    const float4* __restrict__ x4, const int* __restrict__ offs,
    const int* __restrict__ csr, float* __restrict__ out,
    const float* __restrict__ W1, const float* __restrict__ b1,
    const float* __restrict__ W2, const float* __restrict__ b2) {
    __shared__ float sW1[64][64];
    __shared__ float sW2[64][64];
    __shared__ float sb1[64];
    __shared__ float sb2[64];
    __shared__ float sh[8][64];
    __shared__ float sh1[8][64];

    int tid = threadIdx.x;
    for (int i = tid; i < 4096; i += 512) {
        sW1[i >> 6][i & 63] = W1[i];
        sW2[i >> 6][i & 63] = W2[i];
    }
    if (tid < 64) {
        sb1[tid] = b1[tid];
        sb2[tid] = b2[tid];
    }

    int local = tid >> 6;
    int lane = tid & 63;
    int s = lane >> 4;
    int c = lane & 15;
    int node = blockIdx.x * 8 + local;

    int start = (node == 0) ? 0 : offs[node - 1];
    int end = offs[node];

    float4 acc = make_float4(0.f, 0.f, 0.f, 0.f);
    float4 self = x4[(size_t)node * 16 + c];
    if (s == 0) acc = self;

    for (int b = start; b < end; b += 16) {
        int p = b + s;
        int i0 = (p < end) ? csr[p] : -1;
        int i1 = (p + 4 < end) ? csr[p + 4] : -1;
        int i2 = (p + 8 < end) ? csr[p + 8] : -1;
        int i3 = (p + 12 < end) ? csr[p + 12] : -1;
        float4 v0 = x4[(size_t)max(i0, 0) * 16 + c];
        float4 v1 = x4[(size_t)max(i1, 0) * 16 + c];
        float4 v2 = x4[(size_t)max(i2, 0) * 16 + c];
        float4 v3 = x4[(size_t)max(i3, 0) * 16 + c];
        if (i0 >= 0) { acc.x += v0.x; acc.y += v0.y; acc.z += v0.z; acc.w += v0.w; }
        if (i1 >= 0) { acc.x += v1.x; acc.y += v1.y; acc.z += v1.z; acc.w += v1.w; }
        if (i2 >= 0) { acc.x += v2.x; acc.y += v2.y; acc.z += v2.z; acc.w += v2.w; }
        if (i3 >= 0) { acc.x += v3.x; acc.y += v3.y; acc.z += v3.z; acc.w += v3.w; }
    }

    acc.x += __shfl_xor(acc.x, 16); acc.y += __shfl_xor(acc.y, 16);
    acc.z += __shfl_xor(acc.z, 16); acc.w += __shfl_xor(acc.w, 16);
    acc.x += __shfl_xor(acc.x, 32); acc.y += __shfl_xor(acc.y, 32);
    acc.z += __shfl_xor(acc.z, 32); acc.w += __shfl_xor(acc.w, 32);

    __syncthreads();
    if (s == 0) *(float4*)&sh[local][c * 4] = acc;
    __syncthreads();

    int j = lane;
    float a1 = sb1[j];
#pragma unroll
    for (int k = 0; k < 64; ++k) a1 = fmaf(sh[local][k], sW1[k][j], a1);
    a1 = fmaxf(a1, 0.0f);
    sh1[local][j] = a1;
    __syncthreads();

    float a2 = sb2[j];
#pragma unroll
    for (int k = 0; k < 64; ++k) a2 = fmaf(sh1[local][k], sW2[k][j], a2);
    out[(size_t)node * 64 + j] = a2;
}

// ===========================================================================
// Legacy round-4 CSR build (middle fallback if ws too small for bucket sort).
// ===========================================================================
__global__ void zero_ints(int* __restrict__ p, int n) {
    int i = blockIdx.x * blockDim.x + threadIdx.x;
    if (i < n) p[i] = 0;
}

__global__ void count_deg(const int* __restrict__ ei, int* __restrict__ deg) {
    int e = blockIdx.x * blockDim.x + threadIdx.x;
    if (e < N_EDGES) atomicAdd(&deg[ei[N_EDGES + e]], 1);
}

__global__ __launch_bounds__(256) void scan_a(const int* __restrict__ deg,
                                              int* __restrict__ offs,
                                              int* __restrict__ bsum) {
    __shared__ int lds[256];
    int tid = threadIdx.x;
    int base = blockIdx.x * SCAN_CHUNK + tid * 8;
    int v[8], ex[8];
    int run = 0;
#pragma unroll
    for (int k = 0; k < 8; ++k) {
        v[k] = (base + k < N_NODES) ? deg[base + k] : 0;
        ex[k] = run;
        run += v[k];
    }
    lds[tid] = run;
    __syncthreads();
    for (int off = 1; off < 256; off <<= 1) {
        int t = (tid >= off) ? lds[tid - off] : 0;
        __syncthreads();
        lds[tid] += t;
        __syncthreads();
    }
    int prefix = lds[tid] - run;
#pragma unroll
    for (int k = 0; k < 8; ++k)
        if (base + k < N_NODES) offs[base + k] = prefix + ex[k];
    if (tid == 0) bsum[blockIdx.x] = lds[255];
}

__global__ void scan_c(int* __restrict__ offs, const int* __restrict__ bsum) {
    int i = blockIdx.x * blockDim.x + threadIdx.x;
    if (i >= N_NODES) return;
    int chunk = i / SCAN_CHUNK;
    int add = 0;
    for (int t = 0; t < chunk; ++t) add += bsum[t];
    offs[i] += add;
}

__global__ void fill_csr(const int* __restrict__ ei, int* __restrict__ offs,
                         int* __restrict__ csr) {
    int e = blockIdx.x * blockDim.x + threadIdx.x;
    if (e >= N_EDGES) return;
    int src = ei[e];
    int dst = ei[N_EDGES + e];
    int pos = atomicAdd(&offs[dst], 1);
    csr[pos] = src;
}

// ===========================================================================
// Last-resort fp32-atomic path.
// ===========================================================================
__global__ void init_h(const float4* __restrict__ x, float4* __restrict__ h,
                       int n4) {
    int i = blockIdx.x * blockDim.x + threadIdx.x;
    if (i < n4) h[i] = x[i];
}

__global__ void scatter_add(const float4* __restrict__ x4,
                            const int* __restrict__ ei,
                            float* __restrict__ h) {
    long long i = (long long)blockIdx.x * blockDim.x + threadIdx.x;
    if (i >= (long long)N_EDGES * 16) return;
    int e = (int)(i >> 4);
    int lane = (int)(i & 15);
    int src = ei[e];
    int dst = ei[N_EDGES + e];
    float4 v = x4[(long long)src * 16 + lane];
    float* p = h + (long long)dst * 64 + lane * 4;
    unsafeAtomicAdd(p + 0, v.x);
    unsafeAtomicAdd(p + 1, v.y);
    unsafeAtomicAdd(p + 2, v.z);
    unsafeAtomicAdd(p + 3, v.w);
}

__global__ __launch_bounds__(256) void mlp(float* __restrict__ h,
                                           const float* __restrict__ W1,
                                           const float* __restrict__ b1,
                                           const float* __restrict__ W2,
                                           const float* __restrict__ b2) {
    __shared__ float sW1[64][64];
    __shared__ float sW2[64][64];
    __shared__ float sb1[64];
    __shared__ float sb2[64];
    __shared__ float sh[4][64];
    __shared__ float sh1[4][64];
    int tid = threadIdx.x;
    for (int i = tid; i < 4096; i += 256) {
        sW1[i >> 6][i & 63] = W1[i];
        sW2[i >> 6][i & 63] = W2[i];
    }
    if (tid < 64) { sb1[tid] = b1[tid]; sb2[tid] = b2[tid]; }
    __syncthreads();
    int local = tid >> 6, j = tid & 63;
    int node = blockIdx.x * 4 + local;
    sh[local][j] = h[(long long)node * 64 + j];
    __syncthreads();
    float acc = sb1[j];
#pragma unroll
    for (int k = 0; k < 64; ++k) acc = fmaf(sh[local][k], sW1[k][j], acc);
    acc = fmaxf(acc, 0.0f);
    sh1[local][j] = acc;
    __syncthreads();
    float acc2 = sb2[j];
#pragma unroll
    for (int k = 0; k < 64; ++k) acc2 = fmaf(sh1[local][k], sW2[k][j], acc2);
    h[(long long)node * 64 + j] = acc2;
}

extern "C" void kernel_launch(void* const* d_in, const int* in_sizes, int n_in,
                              void* d_out, int out_size, void* d_ws, size_t ws_size,
                              hipStream_t stream) {
    const float* x = (const float*)d_in[0];
    const int* ei = (const int*)d_in[1];   // harness stores ints as int32
    const float* W1 = (const float*)d_in[2];
    const float* b1 = (const float*)d_in[3];
    const float* W2 = (const float*)d_in[4];
    const float* b2 = (const float*)d_in[5];
    float* out = (float*)d_out;

    // New path ws: offs[N] | M[NBLK_A*NB] | bcount[NB] | bbase[NB+1] | binned[E] | csr[E]
    size_t need_new = (size_t)(N_NODES + NBLK_A * NB + NB + (NB + 1) +
                               2 * N_EDGES) * sizeof(int);
    size_t need_mid = (size_t)(2 * N_NODES + SCAN_BLOCKS + N_EDGES) * sizeof(int);

    if (ws_size >= need_new) {
        int* offs = (int*)d_ws;
        int* M = offs + N_NODES;
        int* bcount = M + NBLK_A * NB;
        int* bbase = bcount + NB;
        int* binned = bbase + (NB + 1);
        int* csr = binned + N_EDGES;

        count_buckets<<<NBLK_A, 256, 0, stream>>>(ei, M);
        col_scan<<<(NB + 255) / 256, 256, 0, stream>>>(M, bcount);
        bucket_base<<<1, 512, 0, stream>>>(bcount, bbase);
        bin_edges<<<NBLK_A, 256, 0, stream>>>(ei, M, bbase, binned);
        bucket_sort<<<NB, 256, 0, stream>>>(binned, bbase, csr, offs);
        gather_mlp<<<N_NODES / 8, 512, 0, stream>>>((const float4*)x, offs,
                                                    csr, out, W1, b1, W2, b2);
    } else if (ws_size >= need_mid) {
        int* deg = (int*)d_ws;
        int* offs = deg + N_NODES;
        int* bsum = offs + N_NODES;
        int* csr = bsum + SCAN_BLOCKS;

        zero_ints<<<(N_NODES + 255) / 256, 256, 0, stream>>>(deg, N_NODES);
        count_deg<<<(N_EDGES + 255) / 256, 256, 0, stream>>>(ei, deg);
        scan_a<<<SCAN_BLOCKS, 256, 0, stream>>>(deg, offs, bsum);
        scan_c<<<(N_NODES + 255) / 256, 256, 0, stream>>>(offs, bsum);
        fill_csr<<<(N_EDGES + 255) / 256, 256, 0, stream>>>(ei, offs, csr);
        gather_mlp<<<N_NODES / 8, 512, 0, stream>>>((const float4*)x, offs,
                                                    csr, out, W1, b1, W2, b2);
    } else {
        int n4 = N_NODES * 64 / 4;
        init_h<<<(n4 + 255) / 256, 256, 0, stream>>>((const float4*)x,
                                                     (float4*)out, n4);
        long long nwork = (long long)N_EDGES * 16;
        scatter_add<<<(int)((nwork + 255) / 256), 256, 0, stream>>>(
            (const float4*)x, ei, out);
        mlp<<<N_NODES / 4, 256, 0, stream>>>(out, W1, b1, W2, b2);
    }
}